// Round 11
// baseline (381.560 us; speedup 1.0000x reference)
//
#include <hip/hip_runtime.h>

#define BB 256
#define SS 1024
#define TT 128
#define EN 127          // END state (row EN of trans = -1e4)
#define IMIN -10000.0f
#define L2E 1.4426950408889634f
#define LN2f 0.6931471805599453f

// DPP row_ror helper (rotate within 16-lane row; pure VALU, no DS pipe).
template<int CTRL>
__device__ __forceinline__ float dpp_mov(float x) {
    return __int_as_float(__builtin_amdgcn_update_dpp(
        0, __float_as_int(x), CTRL, 0xF, 0xF, true));
}
// full 16-lane sum via rotate-halving: ror 1,2,4,8 (0x120+n = row_ror:n)
__device__ __forceinline__ float rowsum16(float x) {
    x += dpp_mov<0x121>(x);
    x += dpp_mov<0x122>(x);
    x += dpp_mov<0x124>(x);
    x += dpp_mov<0x128>(x);
    return x;
}

// One block per batch, 512 threads (8 waves). tid = 16*g + c:
// g = row-group (rows 4g..4g+3), c = j-chunk (cols 8c..8c+7).
// TILED matvec: each thread does a 4x8 tile -> reads only 2 ds_read_b128
// of v per step (16/block vs 64 in the 1x32 layout); v reuse across 4 rows
// lives in registers. j-reduction over the 16 c-lanes = DPP row_ror
// (VALU), NOT shfl_xor 4/8 (which lowers to ds_swizzle = DS pipe).
// v chunks stored at float idx 8c + 4*((c>>2)&1): 16 distinct b128 addrs
// hit each 4-bank group exactly 2x -> 2-way (free).
// Anchor shift (dsh = log2 v[0], uniform, no reduce) as r6/r8.
// Step barrier = lgkmcnt-only (leaves the chunk-top HBM prefetch in
// flight; __syncthreads' vmcnt(0) drain cost ~900cy once per chunk).
__global__ __launch_bounds__(512, 1) void crf_fwd(const float* __restrict__ feats,
                                                  const int* __restrict__ blen,
                                                  const float* __restrict__ trans,
                                                  float* __restrict__ out)
{
    const int tid = threadIdx.x;
    const int c   = tid & 15;        // j-chunk
    const int g   = tid >> 4;        // row-group
    const int m3  = c & 3;
    const int wrow = 4 * g + m3;     // this thread's writer row (c<4 writes)
    const int b   = blockIdx.x;

    __shared__ __align__(16) float vst[2][144];        // swizzled v, 128+pad
    __shared__ __align__(16) float featbuf[2][8 * TT];
    __shared__ __align__(16) float wout[TT];
    __shared__ __align__(16) float red[8];

    const float* fb = feats + (size_t)b * (SS * TT);
    const int L = blen[b];

    // stage feature chunk 0: 512 threads x float2 = 1024 floats
    *(float2*)(&featbuf[0][tid * 2]) = *(const float2*)(fb + tid * 2);

    const int voff = 8 * c + 4 * ((c >> 2) & 1);               // read base
    const int widx = 8 * (wrow >> 3) + 4 * ((wrow >> 5) & 1) + (wrow & 7);

    // P tile: rows 4g..4g+3, cols 8c..8c+7, base-2 units
    const float* tb = trans + (4 * g) * TT + 8 * c;
    float4 P0L = *(const float4*)(tb);
    float4 P0H = *(const float4*)(tb + 4);
    float4 P1L = *(const float4*)(tb + TT);
    float4 P1H = *(const float4*)(tb + TT + 4);
    float4 P2L = *(const float4*)(tb + 2 * TT);
    float4 P2H = *(const float4*)(tb + 2 * TT + 4);
    float4 P3L = *(const float4*)(tb + 3 * TT);
    float4 P3H = *(const float4*)(tb + 3 * TT + 4);
#define SC4(Pv) Pv.x *= L2E; Pv.y *= L2E; Pv.z *= L2E; Pv.w *= L2E
    SC4(P0L); SC4(P0H); SC4(P1L); SC4(P1H);
    SC4(P2L); SC4(P2H); SC4(P3L); SC4(P3H);
#undef SC4

    // per-row full-row max (reduce local 8 -> 16 c-lanes; init-only shfl ok)
#define LMAX(Pl, Ph) fmaxf(fmaxf(fmaxf(Pl.x, Pl.y), fmaxf(Pl.z, Pl.w)), \
                           fmaxf(fmaxf(Ph.x, Ph.y), fmaxf(Ph.z, Ph.w)))
    float rm0 = LMAX(P0L, P0H), rm1 = LMAX(P1L, P1H);
    float rm2 = LMAX(P2L, P2H), rm3 = LMAX(P3L, P3H);
#undef LMAX
    #pragma unroll
    for (int off = 1; off < 16; off <<= 1) {
        rm0 = fmaxf(rm0, __shfl_xor(rm0, off));
        rm1 = fmaxf(rm1, __shfl_xor(rm1, off));
        rm2 = fmaxf(rm2, __shfl_xor(rm2, off));
        rm3 = fmaxf(rm3, __shfl_xor(rm3, off));
    }
    // normalize P, per-row sums
#define NRM(Pv, r) Pv.x = exp2f(Pv.x - r); Pv.y = exp2f(Pv.y - r); \
                   Pv.z = exp2f(Pv.z - r); Pv.w = exp2f(Pv.w - r)
    NRM(P0L, rm0); NRM(P0H, rm0); NRM(P1L, rm1); NRM(P1H, rm1);
    NRM(P2L, rm2); NRM(P2H, rm2); NRM(P3L, rm3); NRM(P3H, rm3);
#undef NRM
#define LSUM(Pl, Ph) (((Pl.x + Pl.y) + (Pl.z + Pl.w)) + \
                      ((Ph.x + Ph.y) + (Ph.z + Ph.w)))
    float S0 = LSUM(P0L, P0H), S1 = LSUM(P1L, P1H);
    float S2 = LSUM(P2L, P2H), S3 = LSUM(P3L, P3H);
#undef LSUM
    #pragma unroll
    for (int off = 1; off < 16; off <<= 1) {
        S0 += __shfl_xor(S0, off); S1 += __shfl_xor(S1, off);
        S2 += __shfl_xor(S2, off); S3 += __shfl_xor(S3, off);
    }

    // writer-row constants (ternary select: no runtime-indexed arrays)
    const float rmW = m3 == 0 ? rm0 : m3 == 1 ? rm1 : m3 == 2 ? rm2 : rm3;
    const float SW  = m3 == 0 ? S0  : m3 == 1 ? S1  : m3 == 2 ? S2  : S3;

    // exact step 0 (alpha0 = delta on START, col START = -1e4):
    // A1 = f0*L2E + IMIN*L2E + log2(1 + sum_j 2^T2_ij), anchored at
    // rmc=max(rm,0) so row EN (rm=-14427) degrades gracefully (r4 fix).
    float f0w = fb[wrow];
    float rmc = fmaxf(rmW, 0.f);
    float A1w = fmaf(f0w, L2E, (IMIN * L2E) + rmc +
                     log2f(fmaf(SW, exp2f(rmW - rmc), exp2f(-rmc))));

    if (tid == 0) red[0] = A1w;   // anchor = state 0 (tid0: g=0,c=0)
    __syncthreads();              // also covers featbuf[0] staging
    float sh = red[0];
    if (c < 4) vst[0][widx] = exp2f(A1w - sh);   // v[0]==1 at j=0
    __syncthreads();

    int cur = 0;
    float2 fnx = *(const float2*)(fb + 8 * TT + tid * 2);  // prefetch chunk 1

    for (int ch = 0; ; ++ch) {
        if (8 * ch + 8 < L) {
            // stage chunk ch+1 into idle buffer (step barriers order it),
            // then issue prefetch of ch+2 (stays in flight across the
            // lgkmcnt-only step barriers below)
            *(float2*)(&featbuf[(ch + 1) & 1][tid * 2]) = fnx;
            int cn = min(8 * ch + 16, SS - 8);
            fnx = *(const float2*)(fb + cn * TT + tid * 2);
        }
        const int sLo = (ch == 0) ? 1 : 8 * ch;
        const int sHi = min(8 * ch + 8, L);
        for (int s = sLo; s < sHi; ++s) {
            const float* vp = &vst[cur][voff];
            float v0f = vst[cur][0];
            float fv  = featbuf[ch & 1][((s & 7) << 7) + wrow];
            float4 va  = *(const float4*)(vp);
            float4 vb4 = *(const float4*)(vp + 4);

            float dsh = log2f(v0f);
            float cf  = exp2f(fmaf(fv, L2E, rmW - dsh));

            // 4x8 tile MACs (v reused across 4 rows from registers)
            float p0 = P0L.x * va.x;
            p0 = fmaf(P0L.y, va.y, p0);  p0 = fmaf(P0L.z, va.z, p0);
            p0 = fmaf(P0L.w, va.w, p0);  p0 = fmaf(P0H.x, vb4.x, p0);
            p0 = fmaf(P0H.y, vb4.y, p0); p0 = fmaf(P0H.z, vb4.z, p0);
            p0 = fmaf(P0H.w, vb4.w, p0);
            float p1 = P1L.x * va.x;
            p1 = fmaf(P1L.y, va.y, p1);  p1 = fmaf(P1L.z, va.z, p1);
            p1 = fmaf(P1L.w, va.w, p1);  p1 = fmaf(P1H.x, vb4.x, p1);
            p1 = fmaf(P1H.y, vb4.y, p1); p1 = fmaf(P1H.z, vb4.z, p1);
            p1 = fmaf(P1H.w, vb4.w, p1);
            float p2 = P2L.x * va.x;
            p2 = fmaf(P2L.y, va.y, p2);  p2 = fmaf(P2L.z, va.z, p2);
            p2 = fmaf(P2L.w, va.w, p2);  p2 = fmaf(P2H.x, vb4.x, p2);
            p2 = fmaf(P2H.y, vb4.y, p2); p2 = fmaf(P2H.z, vb4.z, p2);
            p2 = fmaf(P2H.w, vb4.w, p2);
            float p3 = P3L.x * va.x;
            p3 = fmaf(P3L.y, va.y, p3);  p3 = fmaf(P3L.z, va.z, p3);
            p3 = fmaf(P3L.w, va.w, p3);  p3 = fmaf(P3H.x, vb4.x, p3);
            p3 = fmaf(P3H.y, vb4.y, p3); p3 = fmaf(P3H.z, vb4.z, p3);
            p3 = fmaf(P3H.w, vb4.w, p3);

            // 16-lane j-reduction: DPP rotations (VALU pipe)
            p0 = rowsum16(p0); p1 = rowsum16(p1);
            p2 = rowsum16(p2); p3 = rowsum16(p3);

            float totW = m3 == 0 ? p0 : m3 == 1 ? p1 : m3 == 2 ? p2 : p3;
            float vn = cf * totW;
            sh += dsh;
            if (c < 4) vst[cur ^ 1][widx] = vn;
            // lgkmcnt-only barrier: don't drain the global prefetch
            asm volatile("s_waitcnt lgkmcnt(0)\n\ts_barrier" ::: "memory");
            cur ^= 1;
        }
        if (8 * ch + 8 >= L) break;
    }

    __syncthreads();
    // epilogue: out = ln2 * log2 sum_j 2^(sh + log2 v_j + trans[EN][j]*L2E)
    if (tid < TT) {
        int j = tid;
        int ridx = 8 * (j >> 3) + 4 * ((j >> 5) & 1) + (j & 7);
        float vL = vst[cur][ridx];
        wout[j] = fmaf(trans[EN * TT + j], L2E, sh + log2f(vL)); // v=0 -> -inf ok
    }
    __syncthreads();
    if (tid < 64) {
        float w0 = wout[tid], w1 = wout[tid + 64];
        float mm = fmaxf(w0, w1);
        #pragma unroll
        for (int off = 1; off < 64; off <<= 1) mm = fmaxf(mm, __shfl_xor(mm, off));
        float ss = exp2f(w0 - mm) + exp2f(w1 - mm);
        #pragma unroll
        for (int off = 1; off < 64; off <<= 1) ss += __shfl_xor(ss, off);
        if (tid == 0) out[b] = (mm + log2f(ss)) * LN2f;
    }
}

extern "C" void kernel_launch(void* const* d_in, const int* in_sizes, int n_in,
                              void* d_out, int out_size, void* d_ws, size_t ws_size,
                              hipStream_t stream) {
    const float* feats = (const float*)d_in[0];
    const int*   blen  = (const int*)d_in[1];
    const float* trans = (const float*)d_in[2];
    float*       o     = (float*)d_out;
    crf_fwd<<<dim3(BB), dim3(512), 0, stream>>>(feats, blen, trans, o);
}